// Round 5
// baseline (2201.221 us; speedup 1.0000x reference)
//
#include <hip/hip_runtime.h>

typedef _Float16 f16;
typedef _Float16 f16x2 __attribute__((ext_vector_type(2)));
typedef _Float16 f16x4 __attribute__((ext_vector_type(4)));
typedef _Float16 f16x8 __attribute__((ext_vector_type(8)));
typedef float    f32x4 __attribute__((ext_vector_type(4)));

__device__ __forceinline__ float fdot2(f16x2 a, f16x2 b, float c) {
#if __has_builtin(__builtin_amdgcn_fdot2)
  return __builtin_amdgcn_fdot2(a, b, c, false);
#else
  return c + (float)a[0] * (float)b[0] + (float)a[1] * (float)b[1];
#endif
}

template <int I>
__device__ __forceinline__ f16x2 pick(f16x8 v) {
  return f16x2{v[2 * I], v[2 * I + 1]};
}

__device__ __forceinline__ f16x2 rlane(f16x2 src, int lane) {
  return __builtin_bit_cast(f16x2,
      __builtin_amdgcn_readlane(__builtin_bit_cast(int, src), lane));
}

// ---------------- small helper kernels ----------------

__global__ void cvt_f32_to_f16(const float* __restrict__ in, f16* __restrict__ out, int n) {
  int i = (blockIdx.x * blockDim.x + threadIdx.x) * 4;
  if (i + 3 < n) {
    float4 v = *(const float4*)(in + i);
    f16x4 h; h[0] = (f16)v.x; h[1] = (f16)v.y; h[2] = (f16)v.z; h[3] = (f16)v.w;
    *(f16x4*)(out + i) = h;
  }
}

__global__ void bias_comb_kernel(const float* __restrict__ a, const float* __restrict__ b,
                                 float* __restrict__ o, int n) {
  int i = blockIdx.x * blockDim.x + threadIdx.x;
  if (i < n) o[i] = a[i] + b[i];
}

// ---------------- GEMM: C[M,N] = A[M,K] * B[N,K]^T + bias[N] ----------------

#define BM 128
#define BN 128
#define BKT 32
#define LDK 40  // padded leading dim (f16 elems) to dodge bank conflicts

template <bool A_IS_F32>
__global__ __launch_bounds__(256, 2) void gemm_f16_kernel(
    const void* __restrict__ Aptr,    // [M][K]
    const f16* __restrict__ B,        // [N][K]
    const float* __restrict__ bias,   // [N]
    float* __restrict__ C,            // [M][N]
    int M, int N, int K) {
  __shared__ f16 As[BM][LDK];
  __shared__ f16 Bs[BN][LDK];

  const int tid = threadIdx.x;
  const int bm = blockIdx.y, bn = blockIdx.x;
  const int wave = tid >> 6, lane = tid & 63;
  const int wm = wave >> 1, wn = wave & 1;

  f32x4 acc[4][4] = {};

  for (int k0 = 0; k0 < K; k0 += BKT) {
#pragma unroll
    for (int it = 0; it < 2; ++it) {
      int idx = tid + it * 256;          // 0..511
      int row = idx >> 2;                // 0..127
      int kc  = (idx & 3) << 3;          // 0,8,16,24
      if (A_IS_F32) {
        const float* Af = (const float*)Aptr + (size_t)(bm * BM + row) * K + k0 + kc;
        float4 v0 = *(const float4*)Af;
        float4 v1 = *(const float4*)(Af + 4);
        f16x8 h;
        h[0] = (f16)v0.x; h[1] = (f16)v0.y; h[2] = (f16)v0.z; h[3] = (f16)v0.w;
        h[4] = (f16)v1.x; h[5] = (f16)v1.y; h[6] = (f16)v1.z; h[7] = (f16)v1.w;
        *(f16x8*)&As[row][kc] = h;
      } else {
        const f16* Ah = (const f16*)Aptr + (size_t)(bm * BM + row) * K + k0 + kc;
        *(f16x8*)&As[row][kc] = *(const f16x8*)Ah;
      }
      const f16* Bh = B + (size_t)(bn * BN + row) * K + k0 + kc;
      *(f16x8*)&Bs[row][kc] = *(const f16x8*)Bh;
    }
    __syncthreads();

    const int fr = lane & 15;
    const int fk = (lane >> 4) << 3;  // 0,8,16,24
    f16x8 af[4], bf[4];
#pragma unroll
    for (int i = 0; i < 4; ++i) af[i] = *(const f16x8*)&As[wm * 64 + i * 16 + fr][fk];
#pragma unroll
    for (int j = 0; j < 4; ++j) bf[j] = *(const f16x8*)&Bs[wn * 64 + j * 16 + fr][fk];
#pragma unroll
    for (int i = 0; i < 4; ++i)
#pragma unroll
      for (int j = 0; j < 4; ++j)
        acc[i][j] = __builtin_amdgcn_mfma_f32_16x16x32_f16(af[i], bf[j], acc[i][j], 0, 0, 0);
    __syncthreads();
  }

  const int fr = lane & 15;
  const int fq = lane >> 4;
#pragma unroll
  for (int i = 0; i < 4; ++i)
#pragma unroll
    for (int j = 0; j < 4; ++j)
#pragma unroll
      for (int r = 0; r < 4; ++r) {
        int row = bm * BM + wm * 64 + i * 16 + fq * 4 + r;
        int col = bn * BN + wn * 64 + j * 16 + fr;
        C[(size_t)row * N + col] = acc[i][j][r] + bias[col];
      }
}

// ---------------- recurrent scan (split-k, 1024 threads) ----------------
// One block per batch row. Thread = (j = tid&511, kh = tid>>9). Each thread
// computes the k-half [kh*256, kh*256+256) of output j: 128 f16x2 pairs.
//   pairs   0.. 63 : W in VGPR, h via LDS b128 uniform broadcast (16 chunks)
//   pairs  64..103 : W in VGPR, h via v_readlane from per-lane copy (VALU pipe)
//   pairs 104..127 : W in LDS  (f16x4 [12][1024], b64 4-way = cheap), h via readlane
// kh=1 writes partial to LDS; kh=0 combines + xp + tanh, writes h / hs.
// 16 waves = 4/SIMD (reg budget 128 -> KV=104 fits; no AGPR bouncing possible).

#define ST 1024
#define KV 104    // VGPR W pairs
#define KL 12     // LDS W f16x4 entries (= 24 pairs)
#define BC 16     // broadcast h chunks (x4 pairs = 64 pairs)
#define RLV 40    // readlane pairs fed from VGPR W (pairs 64..103)

__global__ __launch_bounds__(ST, 1) void rnn_scan_kernel(
    const f16* __restrict__ Whh,    // [512][512] f16
    const float* __restrict__ h0,   // [B][512] f32
    const float* __restrict__ xp,   // [B][T][512] f32 (pre-activation incl. biases)
    f16* __restrict__ hs,           // [B][T][512] f16 (out, for y-GEMM)
    float* __restrict__ hn,         // [B][512] f32 (out)
    int T) {
  __shared__ f16x4 Wl[KL][ST];                   // 96 KB
  __shared__ __align__(16) f16 hbufF[2][512];    // 2 KB
  __shared__ float part[512];                    // 2 KB

  const int tid  = threadIdx.x;
  const int j    = tid & 511;
  const int kh   = tid >> 9;         // wave-uniform (waves 0..7 -> 0, 8..15 -> 1)
  const int lane = tid & 63;
  const int b    = blockIdx.x;

  // W row j, k-half kh: 128 consecutive f16x2 pairs
  const f16x2* wrow = (const f16x2*)Whh + (size_t)j * 256 + kh * 128;
  f16x2 wreg[KV];
#pragma unroll
  for (int i = 0; i < KV; ++i) wreg[i] = wrow[i];
#pragma unroll
  for (int e = 0; e < KL; ++e)
    Wl[e][tid] = *(const f16x4*)(wrow + KV + 2 * e);

  if (kh == 0) hbufF[0][j] = (f16)h0[(size_t)b * 512 + j];
  __syncthreads();

  const float* xpb = xp + (size_t)b * T * 512 + j;
  f16* hsb = hs + (size_t)b * T * 512 + j;

  int cur = 0;
  float hlast = 0.f;
  float xv = (kh == 0) ? xpb[0] : 0.f;

  for (int t = 0; t < T; ++t) {
    // prefetch next xp (kh==0 only; wave-uniform branch)
    float xn = xv;
    if (kh == 0) {
      int tn = t + 1 < T ? t + 1 : t;
      xn = xpb[(size_t)tn * 512];
    }

    const f16x8* bcp = (const f16x8*)&hbufF[cur][kh * 256];         // chunks 0..15
    const f16x2* rlp = (const f16x2*)&hbufF[cur][kh * 256 + 128];   // pairs 64..127
    f16x2 rsv = rlp[lane];     // lane l holds h-pair (64+l); per-lane b32, 2-way free

    float a0 = xv, a1 = 0.f, a2 = 0.f, a3 = 0.f;

    // --- broadcast-fed pairs 0..63 ---
#pragma unroll
    for (int c = 0; c < BC; ++c) {
      f16x8 hv = bcp[c];                  // uniform address -> LDS broadcast
      a0 = fdot2(wreg[4 * c + 0], pick<0>(hv), a0);
      a1 = fdot2(wreg[4 * c + 1], pick<1>(hv), a1);
      a2 = fdot2(wreg[4 * c + 2], pick<2>(hv), a2);
      a3 = fdot2(wreg[4 * c + 3], pick<3>(hv), a3);
    }
    // --- readlane-fed pairs 64..103 (W in VGPR) ---
#pragma unroll
    for (int p = 0; p < RLV; ++p) {
      f16x2 hv = rlane(rsv, p);           // SGPR broadcast, VALU pipe
      float& a = (p & 3) == 0 ? a0 : (p & 3) == 1 ? a1 : (p & 3) == 2 ? a2 : a3;
      a = fdot2(wreg[64 + p], hv, a);
    }
    // --- readlane-fed pairs 104..127 (W in LDS, b64) ---
#pragma unroll
    for (int e = 0; e < KL; ++e) {
      f16x4 wq = Wl[e][tid];
      int p0 = RLV + 2 * e, p1 = p0 + 1;
      f16x2 h0v = rlane(rsv, p0);
      f16x2 h1v = rlane(rsv, p1);
      float& aa = (p0 & 3) == 0 ? a0 : (p0 & 3) == 1 ? a1 : (p0 & 3) == 2 ? a2 : a3;
      aa = fdot2(f16x2{wq[0], wq[1]}, h0v, aa);
      float& ab = (p1 & 3) == 0 ? a0 : (p1 & 3) == 1 ? a1 : (p1 & 3) == 2 ? a2 : a3;
      ab = fdot2(f16x2{wq[2], wq[3]}, h1v, ab);
    }

    float asum = (a0 + a1) + (a2 + a3);
    if (kh == 1) part[j] = asum;
    __syncthreads();

    if (kh == 0) {
      float acc = asum + part[j];
      // tanh(x) = 1 - 2/(exp(2x)+1); branch-free
      float e = __expf(2.0f * acc);
      float hnew = 1.0f - 2.0f * __builtin_amdgcn_rcpf(e + 1.0f);
      hlast = hnew;
      f16 hh = (f16)hnew;
      hsb[(size_t)t * 512] = hh;
      hbufF[cur ^ 1][j] = hh;
    }
    __syncthreads();
    cur ^= 1;
    xv = xn;
  }
  if (kh == 0) hn[(size_t)b * 512 + j] = hlast;
}

// ---------------- launch ----------------

extern "C" void kernel_launch(void* const* d_in, const int* in_sizes, int n_in,
                              void* d_out, int out_size, void* d_ws, size_t ws_size,
                              hipStream_t stream) {
  const float* x    = (const float*)d_in[0];
  const float* h0   = (const float*)d_in[1];
  const float* W_xh = (const float*)d_in[2];
  const float* b_xh = (const float*)d_in[3];
  const float* W_hh = (const float*)d_in[4];
  const float* b_hh = (const float*)d_in[5];
  const float* W_hy = (const float*)d_in[6];
  const float* b_hy = (const float*)d_in[7];

  const int H = 512;
  const int B = in_sizes[1] / H;            // 64
  const int T = in_sizes[0] / (B * H);      // 1024
  const int M = B * T;                      // 65536

  float* out = (float*)d_out;               // y [M][512] then h_n [B][512]
  float* xpb = out;                         // reuse y region as xp scratch
  float* hn  = out + (size_t)M * H;

  char* w = (char*)d_ws;
  f16*   hsb    = (f16*)w;                                  // M*H*2 bytes
  f16*   Wxh_h  = (f16*)(w + (size_t)M * H * 2);
  f16*   Whh_h  = Wxh_h + H * H;
  f16*   Why_h  = Whh_h + H * H;
  float* biasc  = (float*)(Why_h + H * H);

  const int WN = H * H;  // 262144
  cvt_f32_to_f16<<<WN / 1024, 256, 0, stream>>>(W_xh, Wxh_h, WN);
  cvt_f32_to_f16<<<WN / 1024, 256, 0, stream>>>(W_hh, Whh_h, WN);
  cvt_f32_to_f16<<<WN / 1024, 256, 0, stream>>>(W_hy, Why_h, WN);
  bias_comb_kernel<<<2, 256, 0, stream>>>(b_xh, b_hh, biasc, H);

  // xp = x @ W_xh^T + (b_xh + b_hh)   (written into d_out)
  gemm_f16_kernel<true><<<dim3(H / BN, M / BM), 256, 0, stream>>>(
      x, Wxh_h, biasc, xpb, M, H, H);

  // sequential scan; writes hs (f16, ws) and h_n (f32, d_out tail)
  rnn_scan_kernel<<<B, ST, 0, stream>>>(Whh_h, h0, xpb, hsb, hn, T);

  // y = hs @ W_hy^T + b_hy   (overwrites xp region of d_out)
  gemm_f16_kernel<false><<<dim3(H / BN, M / BM), 256, 0, stream>>>(
      hsb, Why_h, b_hy, out, M, H, H);
}

// Round 6
// 2080.344 us; speedup vs baseline: 1.0581x; 1.0581x over previous
//
#include <hip/hip_runtime.h>

typedef _Float16 f16;
typedef _Float16 f16x2 __attribute__((ext_vector_type(2)));
typedef _Float16 f16x4 __attribute__((ext_vector_type(4)));
typedef _Float16 f16x8 __attribute__((ext_vector_type(8)));
typedef float    f32x4 __attribute__((ext_vector_type(4)));

__device__ __forceinline__ float fdot2(f16x2 a, f16x2 b, float c) {
#if __has_builtin(__builtin_amdgcn_fdot2)
  return __builtin_amdgcn_fdot2(a, b, c, false);
#else
  return c + (float)a[0] * (float)b[0] + (float)a[1] * (float)b[1];
#endif
}

template <int I>
__device__ __forceinline__ f16x2 pick(f16x8 v) {
  return f16x2{v[2 * I], v[2 * I + 1]};
}

__device__ __forceinline__ f16x2 rl(int src, int lane) {
  return __builtin_bit_cast(f16x2, __builtin_amdgcn_readlane(src, lane));
}

// ---------------- small helper kernels ----------------

__global__ void cvt_f32_to_f16(const float* __restrict__ in, f16* __restrict__ out, int n) {
  int i = (blockIdx.x * blockDim.x + threadIdx.x) * 4;
  if (i + 3 < n) {
    float4 v = *(const float4*)(in + i);
    f16x4 h; h[0] = (f16)v.x; h[1] = (f16)v.y; h[2] = (f16)v.z; h[3] = (f16)v.w;
    *(f16x4*)(out + i) = h;
  }
}

__global__ void bias_comb_kernel(const float* __restrict__ a, const float* __restrict__ b,
                                 float* __restrict__ o, int n) {
  int i = blockIdx.x * blockDim.x + threadIdx.x;
  if (i < n) o[i] = a[i] + b[i];
}

// ---------------- GEMM: C[M,N] = A[M,K] * B[N,K]^T + bias[N] ----------------

#define BM 128
#define BN 128
#define BKT 32
#define LDK 40  // padded leading dim (f16 elems) to dodge bank conflicts

template <bool A_IS_F32>
__global__ __launch_bounds__(256, 2) void gemm_f16_kernel(
    const void* __restrict__ Aptr,    // [M][K]
    const f16* __restrict__ B,        // [N][K]
    const float* __restrict__ bias,   // [N]
    float* __restrict__ C,            // [M][N]
    int M, int N, int K) {
  __shared__ f16 As[BM][LDK];
  __shared__ f16 Bs[BN][LDK];

  const int tid = threadIdx.x;
  const int bm = blockIdx.y, bn = blockIdx.x;
  const int wave = tid >> 6, lane = tid & 63;
  const int wm = wave >> 1, wn = wave & 1;

  f32x4 acc[4][4] = {};

  for (int k0 = 0; k0 < K; k0 += BKT) {
#pragma unroll
    for (int it = 0; it < 2; ++it) {
      int idx = tid + it * 256;          // 0..511
      int row = idx >> 2;                // 0..127
      int kc  = (idx & 3) << 3;          // 0,8,16,24
      if (A_IS_F32) {
        const float* Af = (const float*)Aptr + (size_t)(bm * BM + row) * K + k0 + kc;
        float4 v0 = *(const float4*)Af;
        float4 v1 = *(const float4*)(Af + 4);
        f16x8 h;
        h[0] = (f16)v0.x; h[1] = (f16)v0.y; h[2] = (f16)v0.z; h[3] = (f16)v0.w;
        h[4] = (f16)v1.x; h[5] = (f16)v1.y; h[6] = (f16)v1.z; h[7] = (f16)v1.w;
        *(f16x8*)&As[row][kc] = h;
      } else {
        const f16* Ah = (const f16*)Aptr + (size_t)(bm * BM + row) * K + k0 + kc;
        *(f16x8*)&As[row][kc] = *(const f16x8*)Ah;
      }
      const f16* Bh = B + (size_t)(bn * BN + row) * K + k0 + kc;
      *(f16x8*)&Bs[row][kc] = *(const f16x8*)Bh;
    }
    __syncthreads();

    const int fr = lane & 15;
    const int fk = (lane >> 4) << 3;  // 0,8,16,24
    f16x8 af[4], bf[4];
#pragma unroll
    for (int i = 0; i < 4; ++i) af[i] = *(const f16x8*)&As[wm * 64 + i * 16 + fr][fk];
#pragma unroll
    for (int j = 0; j < 4; ++j) bf[j] = *(const f16x8*)&Bs[wn * 64 + j * 16 + fr][fk];
#pragma unroll
    for (int i = 0; i < 4; ++i)
#pragma unroll
      for (int j = 0; j < 4; ++j)
        acc[i][j] = __builtin_amdgcn_mfma_f32_16x16x32_f16(af[i], bf[j], acc[i][j], 0, 0, 0);
    __syncthreads();
  }

  const int fr = lane & 15;
  const int fq = lane >> 4;
#pragma unroll
  for (int i = 0; i < 4; ++i)
#pragma unroll
    for (int j = 0; j < 4; ++j)
#pragma unroll
      for (int r = 0; r < 4; ++r) {
        int row = bm * BM + wm * 64 + i * 16 + fq * 4 + r;
        int col = bn * BN + wn * 64 + j * 16 + fr;
        C[(size_t)row * N + col] = acc[i][j][r] + bias[col];
      }
}

// ---------------- recurrent scan ----------------
// One block (512 thr, 8 waves, 1 block/CU) per batch row; thread tid owns
// output element tid. LDS-pipe-minimized step (the round-0..4 kernels were
// LDS-instruction-bound at ~4100 cyc/step):
//  - 64 k-chunks of 4 f16x2 pairs each. Chunk c pairs live in dwords 0..3 of
//    lane c of the per-lane h copy (ONE ds_read_b128 per wave).
//  - chunks  0..17: h via uniform ds_read_b128 broadcast (LDS has slack)
//  - chunks 18..51: h via v_readlane (imm lane = c, VALU pipe)
//  - chunks 52..63: h via readlane, W via ds_read_b128 from Wl[12][512]
//  - W pairs 0..207 in registers (VGPR or AGPR; dot2 sources them)
// LDS/step/CU ~= 8 waves x (18 bcast + 12 Wb128 + 1 hb128) ~= 1800 cyc
// VALU/step/SIMD ~= 2 x (256 dot2 + 184 readlane + misc) ~= 1900-2700 cyc

#define RT 512
#define XB 18     // broadcast-fed chunks
#define KVC 52    // chunks with W in registers (208 pairs)
#define NLC 12    // chunks with W in LDS (64 - KVC)

__global__ __launch_bounds__(RT, 1) void rnn_scan_kernel(
    const f16* __restrict__ Whh,    // [512][512] f16
    const float* __restrict__ h0,   // [B][512] f32
    const float* __restrict__ xp,   // [B][T][512] f32 (pre-activation incl. biases)
    f16* __restrict__ hs,           // [B][T][512] f16 (out, for y-GEMM)
    float* __restrict__ hn,         // [B][512] f32 (out)
    int T) {
  __shared__ f16x8 Wl[NLC][RT];                  // 96 KB
  __shared__ __align__(16) f16 hbuf[2][RT];      // 2 KB

  const int tid  = threadIdx.x;
  const int lane = tid & 63;
  const int b    = blockIdx.x;

  const f16x2* wrow = (const f16x2*)(Whh + (size_t)tid * 512);
  f16x2 wreg[KVC * 4];
#pragma unroll
  for (int i = 0; i < KVC * 4; ++i) wreg[i] = wrow[i];
#pragma unroll
  for (int c = 0; c < NLC; ++c)
    Wl[c][tid] = *(const f16x8*)(wrow + (KVC + c) * 4);

  hbuf[0][tid] = (f16)h0[(size_t)b * 512 + tid];
  __syncthreads();

  const float* xpb = xp + (size_t)b * T * 512 + tid;
  f16* hsb = hs + (size_t)b * T * 512 + tid;

  int cur = 0;
  float hlast = 0.f;
  float xv = xpb[0];
  for (int t = 0; t < T; ++t) {
    int tn = t + 1 < T ? t + 1 : t;
    float xn = xpb[(size_t)tn * 512];   // prefetch next step's xp

    const f16x8* bcp = (const f16x8*)hbuf[cur];
    f16x8 hl = bcp[lane];               // per-lane h copy: pairs 4*lane+d
    int4 hli = __builtin_bit_cast(int4, hl);

    float a0 = xv, a1 = 0.f, a2 = 0.f, a3 = 0.f;
#pragma unroll
    for (int c = 0; c < 64; ++c) {
      f16x2 h0v, h1v, h2v, h3v;
      if (c < XB) {
        f16x8 hv = bcp[c];              // uniform address -> LDS broadcast
        h0v = pick<0>(hv); h1v = pick<1>(hv); h2v = pick<2>(hv); h3v = pick<3>(hv);
      } else {
        h0v = rl(hli.x, c); h1v = rl(hli.y, c);   // VALU-pipe broadcast
        h2v = rl(hli.z, c); h3v = rl(hli.w, c);
      }
      f16x2 w0, w1, w2, w3;
      if (c < KVC) {
        w0 = wreg[4 * c + 0]; w1 = wreg[4 * c + 1];
        w2 = wreg[4 * c + 2]; w3 = wreg[4 * c + 3];
      } else {
        f16x8 wv = Wl[c - KVC][tid];
        w0 = pick<0>(wv); w1 = pick<1>(wv); w2 = pick<2>(wv); w3 = pick<3>(wv);
      }
      a0 = fdot2(w0, h0v, a0);
      a1 = fdot2(w1, h1v, a1);
      a2 = fdot2(w2, h2v, a2);
      a3 = fdot2(w3, h3v, a3);
    }

    float acc = (a0 + a1) + (a2 + a3);
    // tanh(x) = 1 - 2/(exp(2x)+1); branch-free
    float e = __expf(2.0f * acc);
    float hnew = 1.0f - 2.0f * __builtin_amdgcn_rcpf(e + 1.0f);
    hlast = hnew;
    f16 hh = (f16)hnew;
    hsb[(size_t)t * 512] = hh;
    hbuf[cur ^ 1][tid] = hh;
    __syncthreads();
    cur ^= 1;
    xv = xn;
  }
  hn[(size_t)b * 512 + tid] = hlast;
}

// ---------------- launch ----------------

extern "C" void kernel_launch(void* const* d_in, const int* in_sizes, int n_in,
                              void* d_out, int out_size, void* d_ws, size_t ws_size,
                              hipStream_t stream) {
  const float* x    = (const float*)d_in[0];
  const float* h0   = (const float*)d_in[1];
  const float* W_xh = (const float*)d_in[2];
  const float* b_xh = (const float*)d_in[3];
  const float* W_hh = (const float*)d_in[4];
  const float* b_hh = (const float*)d_in[5];
  const float* W_hy = (const float*)d_in[6];
  const float* b_hy = (const float*)d_in[7];

  const int H = 512;
  const int B = in_sizes[1] / H;            // 64
  const int T = in_sizes[0] / (B * H);      // 1024
  const int M = B * T;                      // 65536

  float* out = (float*)d_out;               // y [M][512] then h_n [B][512]
  float* xpb = out;                         // reuse y region as xp scratch
  float* hn  = out + (size_t)M * H;

  char* w = (char*)d_ws;
  f16*   hsb    = (f16*)w;                                  // M*H*2 bytes
  f16*   Wxh_h  = (f16*)(w + (size_t)M * H * 2);
  f16*   Whh_h  = Wxh_h + H * H;
  f16*   Why_h  = Whh_h + H * H;
  float* biasc  = (float*)(Why_h + H * H);

  const int WN = H * H;  // 262144
  cvt_f32_to_f16<<<WN / 1024, 256, 0, stream>>>(W_xh, Wxh_h, WN);
  cvt_f32_to_f16<<<WN / 1024, 256, 0, stream>>>(W_hh, Whh_h, WN);
  cvt_f32_to_f16<<<WN / 1024, 256, 0, stream>>>(W_hy, Why_h, WN);
  bias_comb_kernel<<<2, 256, 0, stream>>>(b_xh, b_hh, biasc, H);

  // xp = x @ W_xh^T + (b_xh + b_hh)   (written into d_out)
  gemm_f16_kernel<true><<<dim3(H / BN, M / BM), 256, 0, stream>>>(
      x, Wxh_h, biasc, xpb, M, H, H);

  // sequential scan; writes hs (f16, ws) and h_n (f32, d_out tail)
  rnn_scan_kernel<<<B, RT, 0, stream>>>(Whh_h, h0, xpb, hsb, hn, T);

  // y = hs @ W_hy^T + b_hy   (overwrites xp region of d_out)
  gemm_f16_kernel<false><<<dim3(H / BN, M / BM), 256, 0, stream>>>(
      hsb, Why_h, b_hy, out, M, H, H);
}

// Round 7
// 852.815 us; speedup vs baseline: 2.5811x; 2.4394x over previous
//
#include <hip/hip_runtime.h>

typedef _Float16 f16;
typedef _Float16 f16x2 __attribute__((ext_vector_type(2)));
typedef _Float16 f16x4 __attribute__((ext_vector_type(4)));
typedef _Float16 f16x8 __attribute__((ext_vector_type(8)));
typedef float    f32x4 __attribute__((ext_vector_type(4)));

__device__ __forceinline__ int sdot4(int a, int b, int c) {
#if __has_builtin(__builtin_amdgcn_sdot4)
  return __builtin_amdgcn_sdot4(a, b, c, false);
#else
#pragma unroll
  for (int i = 0; i < 4; ++i)
    c += ((a << (24 - 8 * i)) >> 24) * ((b << (24 - 8 * i)) >> 24);
  return c;
#endif
}

// ---------------- small helper kernels ----------------

__global__ void cvt_f32_to_f16(const float* __restrict__ in, f16* __restrict__ out, int n) {
  int i = (blockIdx.x * blockDim.x + threadIdx.x) * 4;
  if (i + 3 < n) {
    float4 v = *(const float4*)(in + i);
    f16x4 h; h[0] = (f16)v.x; h[1] = (f16)v.y; h[2] = (f16)v.z; h[3] = (f16)v.w;
    *(f16x4*)(out + i) = h;
  }
}

__global__ void bias_comb_kernel(const float* __restrict__ a, const float* __restrict__ b,
                                 float* __restrict__ o, int n) {
  int i = blockIdx.x * blockDim.x + threadIdx.x;
  if (i < n) o[i] = a[i] + b[i];
}

__global__ void zero_u32_kernel(unsigned* p) { *p = 0u; }

// abs-max of W into *out (uint-ordered float bits; all values >= 0)
__global__ void wabsmax_kernel(const float* __restrict__ in, int n, unsigned* out) {
  float m = 0.f;
  for (int i = blockIdx.x * blockDim.x + threadIdx.x; i < n; i += gridDim.x * blockDim.x)
    m = fmaxf(m, fabsf(in[i]));
#pragma unroll
  for (int off = 32; off >= 1; off >>= 1)
    m = fmaxf(m, __shfl_xor(m, off));
  if ((threadIdx.x & 63) == 0) atomicMax(out, __float_as_uint(m));
}

// quantize W to i8 with scale s = wmax/127
__global__ void quant_w_kernel(const float* __restrict__ W, signed char* __restrict__ out,
                               const unsigned* __restrict__ wmax, int n) {
  float mx = __uint_as_float(*wmax);
  float inv = mx > 0.f ? 127.f / mx : 0.f;
  int i = (blockIdx.x * blockDim.x + threadIdx.x) * 4;
  if (i + 3 < n) {
    float4 v = *(const float4*)(W + i);
    int q0 = (int)__builtin_rintf(v.x * inv);
    int q1 = (int)__builtin_rintf(v.y * inv);
    int q2 = (int)__builtin_rintf(v.z * inv);
    int q3 = (int)__builtin_rintf(v.w * inv);
    unsigned p = (unsigned)(q0 & 255) | ((unsigned)(q1 & 255) << 8) |
                 ((unsigned)(q2 & 255) << 16) | ((unsigned)(q3 & 255) << 24);
    *(unsigned*)(out + i) = p;
  }
}

// ---------------- GEMM: C[M,N] = A[M,K] * B[N,K]^T + bias[N] ----------------

#define BM 128
#define BN 128
#define BKT 32
#define LDK 40  // padded leading dim (f16 elems) to dodge bank conflicts

template <bool A_IS_F32>
__global__ __launch_bounds__(256, 2) void gemm_f16_kernel(
    const void* __restrict__ Aptr,    // [M][K]
    const f16* __restrict__ B,        // [N][K]
    const float* __restrict__ bias,   // [N]
    float* __restrict__ C,            // [M][N]
    int M, int N, int K) {
  __shared__ f16 As[BM][LDK];
  __shared__ f16 Bs[BN][LDK];

  const int tid = threadIdx.x;
  const int bm = blockIdx.y, bn = blockIdx.x;
  const int wave = tid >> 6, lane = tid & 63;
  const int wm = wave >> 1, wn = wave & 1;

  f32x4 acc[4][4] = {};

  for (int k0 = 0; k0 < K; k0 += BKT) {
#pragma unroll
    for (int it = 0; it < 2; ++it) {
      int idx = tid + it * 256;          // 0..511
      int row = idx >> 2;                // 0..127
      int kc  = (idx & 3) << 3;          // 0,8,16,24
      if (A_IS_F32) {
        const float* Af = (const float*)Aptr + (size_t)(bm * BM + row) * K + k0 + kc;
        float4 v0 = *(const float4*)Af;
        float4 v1 = *(const float4*)(Af + 4);
        f16x8 h;
        h[0] = (f16)v0.x; h[1] = (f16)v0.y; h[2] = (f16)v0.z; h[3] = (f16)v0.w;
        h[4] = (f16)v1.x; h[5] = (f16)v1.y; h[6] = (f16)v1.z; h[7] = (f16)v1.w;
        *(f16x8*)&As[row][kc] = h;
      } else {
        const f16* Ah = (const f16*)Aptr + (size_t)(bm * BM + row) * K + k0 + kc;
        *(f16x8*)&As[row][kc] = *(const f16x8*)Ah;
      }
      const f16* Bh = B + (size_t)(bn * BN + row) * K + k0 + kc;
      *(f16x8*)&Bs[row][kc] = *(const f16x8*)Bh;
    }
    __syncthreads();

    const int fr = lane & 15;
    const int fk = (lane >> 4) << 3;  // 0,8,16,24
    f16x8 af[4], bf[4];
#pragma unroll
    for (int i = 0; i < 4; ++i) af[i] = *(const f16x8*)&As[wm * 64 + i * 16 + fr][fk];
#pragma unroll
    for (int j = 0; j < 4; ++j) bf[j] = *(const f16x8*)&Bs[wn * 64 + j * 16 + fr][fk];
#pragma unroll
    for (int i = 0; i < 4; ++i)
#pragma unroll
      for (int j = 0; j < 4; ++j)
        acc[i][j] = __builtin_amdgcn_mfma_f32_16x16x32_f16(af[i], bf[j], acc[i][j], 0, 0, 0);
    __syncthreads();
  }

  const int fr = lane & 15;
  const int fq = lane >> 4;
#pragma unroll
  for (int i = 0; i < 4; ++i)
#pragma unroll
    for (int j = 0; j < 4; ++j)
#pragma unroll
      for (int r = 0; r < 4; ++r) {
        int row = bm * BM + wm * 64 + i * 16 + fq * 4 + r;
        int col = bn * BN + wn * 64 + j * 16 + fr;
        C[(size_t)row * N + col] = acc[i][j][r] + bias[col];
      }
}

// ---------------- recurrent scan (int8 dot4) ----------------
// One block (512 thr, 8 waves, 1 block/CU) per batch row; thread tid owns
// output element tid. W_hh row tid quantized to i8: 512 B = 128 dwords -> fits
// ENTIRELY in the 128-VGPR budget (no AGPR bounce, no LDS W traffic).
// h quantized to i8 by its producer thread each step (h in (-1,1), scale 127);
// h delivery = 32 uniform ds_read_b128 broadcasts per thread per step.
// Per-step budget: VALU ~ 128 sdot4 + ~25 misc; LDS ~ 8 waves x 32 x ~3.7 cyc.

#define RT 512

__global__ __launch_bounds__(RT, 1) void rnn_scan_kernel(
    const signed char* __restrict__ Whq,  // [512][512] i8
    const unsigned* __restrict__ wmax,    // scale source
    const float* __restrict__ h0,         // [B][512] f32
    const float* __restrict__ xp,         // [B][T][512] f32 (pre-act incl. biases)
    f16* __restrict__ hs,                 // [B][T][512] f16 (out, for y-GEMM)
    float* __restrict__ hn,               // [B][512] f32 (out)
    int T) {
  __shared__ __align__(16) signed char hbuf[2][RT];   // 1 KB
  const int tid = threadIdx.x;
  const int b   = blockIdx.x;

  // combined dequant scale: value = acc_int * (wmax/127) * (1/127)
  const float qs = __uint_as_float(*wmax) * (1.0f / 16129.0f);

  // W row tid: 128 dwords of packed i8
  const int* wrow = (const int*)(Whq + (size_t)tid * 512);
  int wq[128];
#pragma unroll
  for (int i = 0; i < 128; ++i) wq[i] = wrow[i];

  {
    float hv = h0[(size_t)b * 512 + tid];
    hv = fminf(1.f, fmaxf(-1.f, hv));
    hbuf[0][tid] = (signed char)(int)__builtin_rintf(127.f * hv);
  }
  __syncthreads();

  const float* xpb = xp + (size_t)b * T * 512 + tid;
  f16* hsb = hs + (size_t)b * T * 512 + tid;

  int cur = 0;
  float hlast = 0.f;
  float xv = xpb[0];
  for (int t = 0; t < T; ++t) {
    int tn = t + 1 < T ? t + 1 : t;
    float xn = xpb[(size_t)tn * 512];   // prefetch next step's xp

    const int4* bcp = (const int4*)hbuf[cur];
    int a0 = 0, a1 = 0, a2 = 0, a3 = 0;
#pragma unroll
    for (int c = 0; c < 32; ++c) {
      int4 hv = bcp[c];                 // uniform address -> LDS b128 broadcast
      a0 = sdot4(wq[4 * c + 0], hv.x, a0);
      a1 = sdot4(wq[4 * c + 1], hv.y, a1);
      a2 = sdot4(wq[4 * c + 2], hv.z, a2);
      a3 = sdot4(wq[4 * c + 3], hv.w, a3);
    }
    float acc = (float)((a0 + a1) + (a2 + a3)) * qs + xv;
    // tanh(x) = 1 - 2/(exp(2x)+1); branch-free
    float e = __expf(2.0f * acc);
    float hnew = 1.0f - 2.0f * __builtin_amdgcn_rcpf(e + 1.0f);
    hlast = hnew;
    hsb[(size_t)t * 512] = (f16)hnew;
    hbuf[cur ^ 1][tid] = (signed char)(int)__builtin_rintf(127.f * hnew);
    __syncthreads();
    cur ^= 1;
    xv = xn;
  }
  hn[(size_t)b * 512 + tid] = hlast;
}

// ---------------- launch ----------------

extern "C" void kernel_launch(void* const* d_in, const int* in_sizes, int n_in,
                              void* d_out, int out_size, void* d_ws, size_t ws_size,
                              hipStream_t stream) {
  const float* x    = (const float*)d_in[0];
  const float* h0   = (const float*)d_in[1];
  const float* W_xh = (const float*)d_in[2];
  const float* b_xh = (const float*)d_in[3];
  const float* W_hh = (const float*)d_in[4];
  const float* b_hh = (const float*)d_in[5];
  const float* W_hy = (const float*)d_in[6];
  const float* b_hy = (const float*)d_in[7];

  const int H = 512;
  const int B = in_sizes[1] / H;            // 64
  const int T = in_sizes[0] / (B * H);      // 1024
  const int M = B * T;                      // 65536

  float* out = (float*)d_out;               // y [M][512] then h_n [B][512]
  float* xpb = out;                         // reuse y region as xp scratch
  float* hn  = out + (size_t)M * H;

  char* w = (char*)d_ws;
  f16*         hsb    = (f16*)w;                              // M*H*2 bytes
  f16*         Wxh_h  = (f16*)(w + (size_t)M * H * 2);        // H*H f16
  f16*         Why_h  = Wxh_h + H * H;                        // H*H f16
  signed char* Whq    = (signed char*)(Why_h + H * H);        // H*H i8
  float*       biasc  = (float*)(Whq + H * H);                // H f32
  unsigned*    wmax   = (unsigned*)(biasc + H);               // 1 u32

  const int WN = H * H;  // 262144
  cvt_f32_to_f16<<<WN / 1024, 256, 0, stream>>>(W_xh, Wxh_h, WN);
  cvt_f32_to_f16<<<WN / 1024, 256, 0, stream>>>(W_hy, Why_h, WN);
  bias_comb_kernel<<<2, 256, 0, stream>>>(b_xh, b_hh, biasc, H);

  // quantize W_hh to i8 with measured absmax scale
  zero_u32_kernel<<<1, 1, 0, stream>>>(wmax);
  wabsmax_kernel<<<64, 256, 0, stream>>>(W_hh, WN, wmax);
  quant_w_kernel<<<WN / 1024, 256, 0, stream>>>(W_hh, Whq, wmax, WN);

  // xp = x @ W_xh^T + (b_xh + b_hh)   (written into d_out)
  gemm_f16_kernel<true><<<dim3(H / BN, M / BM), 256, 0, stream>>>(
      x, Wxh_h, biasc, xpb, M, H, H);

  // sequential scan; writes hs (f16, ws) and h_n (f32, d_out tail)
  rnn_scan_kernel<<<B, RT, 0, stream>>>(Whq, wmax, h0, xpb, hsb, hn, T);

  // y = hs @ W_hy^T + b_hy   (overwrites xp region of d_out)
  gemm_f16_kernel<false><<<dim3(H / BN, M / BM), 256, 0, stream>>>(
      hsb, Why_h, b_hy, out, M, H, H);
}

// Round 8
// 851.880 us; speedup vs baseline: 2.5840x; 1.0011x over previous
//
#include <hip/hip_runtime.h>

typedef _Float16 f16;
typedef _Float16 f16x2 __attribute__((ext_vector_type(2)));
typedef _Float16 f16x4 __attribute__((ext_vector_type(4)));
typedef _Float16 f16x8 __attribute__((ext_vector_type(8)));
typedef float    f32x4 __attribute__((ext_vector_type(4)));

__device__ __forceinline__ int sdot4(int a, int b, int c) {
#if __has_builtin(__builtin_amdgcn_sdot4)
  return __builtin_amdgcn_sdot4(a, b, c, false);
#else
#pragma unroll
  for (int i = 0; i < 4; ++i)
    c += ((a << (24 - 8 * i)) >> 24) * ((b << (24 - 8 * i)) >> 24);
  return c;
#endif
}

// ---------------- small helper kernels ----------------

__global__ void cvt_f32_to_f16(const float* __restrict__ in, f16* __restrict__ out, int n) {
  int i = (blockIdx.x * blockDim.x + threadIdx.x) * 4;
  if (i + 3 < n) {
    float4 v = *(const float4*)(in + i);
    f16x4 h; h[0] = (f16)v.x; h[1] = (f16)v.y; h[2] = (f16)v.z; h[3] = (f16)v.w;
    *(f16x4*)(out + i) = h;
  }
}

__global__ void bias_comb_kernel(const float* __restrict__ a, const float* __restrict__ b,
                                 float* __restrict__ o, int n) {
  int i = blockIdx.x * blockDim.x + threadIdx.x;
  if (i < n) o[i] = a[i] + b[i];
}

__global__ void zero_u32_kernel(unsigned* p) { *p = 0u; }

// abs-max of W into *out (uint-ordered float bits; all values >= 0)
__global__ void wabsmax_kernel(const float* __restrict__ in, int n, unsigned* out) {
  float m = 0.f;
  for (int i = blockIdx.x * blockDim.x + threadIdx.x; i < n; i += gridDim.x * blockDim.x)
    m = fmaxf(m, fabsf(in[i]));
#pragma unroll
  for (int off = 32; off >= 1; off >>= 1)
    m = fmaxf(m, __shfl_xor(m, off));
  if ((threadIdx.x & 63) == 0) atomicMax(out, __float_as_uint(m));
}

// quantize W to i8 with scale s = wmax/127
__global__ void quant_w_kernel(const float* __restrict__ W, signed char* __restrict__ out,
                               const unsigned* __restrict__ wmax, int n) {
  float mx = __uint_as_float(*wmax);
  float inv = mx > 0.f ? 127.f / mx : 0.f;
  int i = (blockIdx.x * blockDim.x + threadIdx.x) * 4;
  if (i + 3 < n) {
    float4 v = *(const float4*)(W + i);
    int q0 = (int)__builtin_rintf(v.x * inv);
    int q1 = (int)__builtin_rintf(v.y * inv);
    int q2 = (int)__builtin_rintf(v.z * inv);
    int q3 = (int)__builtin_rintf(v.w * inv);
    unsigned p = (unsigned)(q0 & 255) | ((unsigned)(q1 & 255) << 8) |
                 ((unsigned)(q2 & 255) << 16) | ((unsigned)(q3 & 255) << 24);
    *(unsigned*)(out + i) = p;
  }
}

// ---------------- GEMM: C[M,N] = A[M,K] * B[N,K]^T + bias[N] ----------------

#define BM 128
#define BN 128
#define BKT 32
#define LDK 40  // padded leading dim (f16 elems) to dodge bank conflicts

template <bool A_IS_F32>
__global__ __launch_bounds__(256, 2) void gemm_f16_kernel(
    const void* __restrict__ Aptr,    // [M][K]
    const f16* __restrict__ B,        // [N][K]
    const float* __restrict__ bias,   // [N]
    float* __restrict__ C,            // [M][N]
    int M, int N, int K) {
  __shared__ f16 As[BM][LDK];
  __shared__ f16 Bs[BN][LDK];

  const int tid = threadIdx.x;
  const int bm = blockIdx.y, bn = blockIdx.x;
  const int wave = tid >> 6, lane = tid & 63;
  const int wm = wave >> 1, wn = wave & 1;

  f32x4 acc[4][4] = {};

  for (int k0 = 0; k0 < K; k0 += BKT) {
#pragma unroll
    for (int it = 0; it < 2; ++it) {
      int idx = tid + it * 256;          // 0..511
      int row = idx >> 2;                // 0..127
      int kc  = (idx & 3) << 3;          // 0,8,16,24
      if (A_IS_F32) {
        const float* Af = (const float*)Aptr + (size_t)(bm * BM + row) * K + k0 + kc;
        float4 v0 = *(const float4*)Af;
        float4 v1 = *(const float4*)(Af + 4);
        f16x8 h;
        h[0] = (f16)v0.x; h[1] = (f16)v0.y; h[2] = (f16)v0.z; h[3] = (f16)v0.w;
        h[4] = (f16)v1.x; h[5] = (f16)v1.y; h[6] = (f16)v1.z; h[7] = (f16)v1.w;
        *(f16x8*)&As[row][kc] = h;
      } else {
        const f16* Ah = (const f16*)Aptr + (size_t)(bm * BM + row) * K + k0 + kc;
        *(f16x8*)&As[row][kc] = *(const f16x8*)Ah;
      }
      const f16* Bh = B + (size_t)(bn * BN + row) * K + k0 + kc;
      *(f16x8*)&Bs[row][kc] = *(const f16x8*)Bh;
    }
    __syncthreads();

    const int fr = lane & 15;
    const int fk = (lane >> 4) << 3;  // 0,8,16,24
    f16x8 af[4], bf[4];
#pragma unroll
    for (int i = 0; i < 4; ++i) af[i] = *(const f16x8*)&As[wm * 64 + i * 16 + fr][fk];
#pragma unroll
    for (int j = 0; j < 4; ++j) bf[j] = *(const f16x8*)&Bs[wn * 64 + j * 16 + fr][fk];
#pragma unroll
    for (int i = 0; i < 4; ++i)
#pragma unroll
      for (int j = 0; j < 4; ++j)
        acc[i][j] = __builtin_amdgcn_mfma_f32_16x16x32_f16(af[i], bf[j], acc[i][j], 0, 0, 0);
    __syncthreads();
  }

  const int fr = lane & 15;
  const int fq = lane >> 4;
#pragma unroll
  for (int i = 0; i < 4; ++i)
#pragma unroll
    for (int j = 0; j < 4; ++j)
#pragma unroll
      for (int r = 0; r < 4; ++r) {
        int row = bm * BM + wm * 64 + i * 16 + fq * 4 + r;
        int col = bn * BN + wn * 64 + j * 16 + fr;
        C[(size_t)row * N + col] = acc[i][j][r] + bias[col];
      }
}

// ---------------- recurrent scan (int8 dot4, register-pinned W) ----------------
// One block (512 thr, 8 waves, 1 block/CU) per batch row; thread tid owns
// output element tid. W_hh row tid quantized to i8: 512 B = 128 dwords, loaded
// once and PINNED into VGPRs via an opaque asm def (defeats the compiler's
// load-rematerialization, which round 7 counters showed: VGPR_Count=84 and
// per-step W re-loads from L2). h quantized to i8 by its producer each step;
// h delivery = 32 uniform ds_read_b128 broadcasts per thread per step.
// Pipe model w/ resident W: VALU ~630 cyc/SIMD, LDS ~950 cyc/CU -> ~1100 cyc.

#define RT 512

__global__ __launch_bounds__(RT, 1) void rnn_scan_kernel(
    const signed char* __restrict__ Whq,  // [512][512] i8
    const unsigned* __restrict__ wmax,    // scale source
    const float* __restrict__ h0,         // [B][512] f32
    const float* __restrict__ xp,         // [B][T][512] f32 (pre-act incl. biases)
    f16* __restrict__ hs,                 // [B][T][512] f16 (out, for y-GEMM)
    float* __restrict__ hn,               // [B][512] f32 (out)
    int T) {
  __shared__ __align__(16) signed char hbuf[2][RT];   // 1 KB
  const int tid = threadIdx.x;
  const int b   = blockIdx.x;

  // combined dequant scale: value = acc_int * (wmax/127) * (1/127)
  const float qs = __uint_as_float(*wmax) * (1.0f / 16129.0f);

  // W row tid: 128 dwords of packed i8 -> load once, pin in VGPRs
  const int* wrow = (const int*)(Whq + (size_t)tid * 512);
  int wq[128];
#pragma unroll
  for (int i = 0; i < 128; ++i) wq[i] = wrow[i];
#pragma unroll
  for (int i = 0; i < 128; ++i)
    asm volatile("" : "+v"(wq[i]));   // opaque def: not rematerializable

  {
    float hv = h0[(size_t)b * 512 + tid];
    hv = fminf(1.f, fmaxf(-1.f, hv));
    hbuf[0][tid] = (signed char)(int)__builtin_rintf(127.f * hv);
  }
  __syncthreads();

  const float* xpb = xp + (size_t)b * T * 512 + tid;
  f16* hsb = hs + (size_t)b * T * 512 + tid;

  int cur = 0;
  float hlast = 0.f;
  float xv = xpb[0];
  for (int t = 0; t < T; ++t) {
    int tn = t + 1 < T ? t + 1 : t;
    float xn = xpb[(size_t)tn * 512];   // prefetch next step's xp

    const int4* bcp = (const int4*)hbuf[cur];
    int a0 = 0, a1 = 0, a2 = 0, a3 = 0;
#pragma unroll
    for (int c = 0; c < 32; ++c) {
      int4 hv = bcp[c];                 // uniform address -> LDS b128 broadcast
      a0 = sdot4(wq[4 * c + 0], hv.x, a0);
      a1 = sdot4(wq[4 * c + 1], hv.y, a1);
      a2 = sdot4(wq[4 * c + 2], hv.z, a2);
      a3 = sdot4(wq[4 * c + 3], hv.w, a3);
    }
    float acc = (float)((a0 + a1) + (a2 + a3)) * qs + xv;
    // tanh(x) = 1 - 2/(exp(2x)+1); branch-free
    float e = __expf(2.0f * acc);
    float hnew = 1.0f - 2.0f * __builtin_amdgcn_rcpf(e + 1.0f);
    hlast = hnew;
    hsb[(size_t)t * 512] = (f16)hnew;
    hbuf[cur ^ 1][tid] = (signed char)(int)__builtin_rintf(127.f * hnew);
    __syncthreads();
    cur ^= 1;
    xv = xn;
  }
  hn[(size_t)b * 512 + tid] = hlast;
}

// ---------------- launch ----------------

extern "C" void kernel_launch(void* const* d_in, const int* in_sizes, int n_in,
                              void* d_out, int out_size, void* d_ws, size_t ws_size,
                              hipStream_t stream) {
  const float* x    = (const float*)d_in[0];
  const float* h0   = (const float*)d_in[1];
  const float* W_xh = (const float*)d_in[2];
  const float* b_xh = (const float*)d_in[3];
  const float* W_hh = (const float*)d_in[4];
  const float* b_hh = (const float*)d_in[5];
  const float* W_hy = (const float*)d_in[6];
  const float* b_hy = (const float*)d_in[7];

  const int H = 512;
  const int B = in_sizes[1] / H;            // 64
  const int T = in_sizes[0] / (B * H);      // 1024
  const int M = B * T;                      // 65536

  float* out = (float*)d_out;               // y [M][512] then h_n [B][512]
  float* xpb = out;                         // reuse y region as xp scratch
  float* hn  = out + (size_t)M * H;

  char* w = (char*)d_ws;
  f16*         hsb    = (f16*)w;                              // M*H*2 bytes
  f16*         Wxh_h  = (f16*)(w + (size_t)M * H * 2);        // H*H f16
  f16*         Why_h  = Wxh_h + H * H;                        // H*H f16
  signed char* Whq    = (signed char*)(Why_h + H * H);        // H*H i8
  float*       biasc  = (float*)(Whq + H * H);                // H f32
  unsigned*    wmax   = (unsigned*)(biasc + H);               // 1 u32

  const int WN = H * H;  // 262144
  cvt_f32_to_f16<<<WN / 1024, 256, 0, stream>>>(W_xh, Wxh_h, WN);
  cvt_f32_to_f16<<<WN / 1024, 256, 0, stream>>>(W_hy, Why_h, WN);
  bias_comb_kernel<<<2, 256, 0, stream>>>(b_xh, b_hh, biasc, H);

  // quantize W_hh to i8 with measured absmax scale
  zero_u32_kernel<<<1, 1, 0, stream>>>(wmax);
  wabsmax_kernel<<<64, 256, 0, stream>>>(W_hh, WN, wmax);
  quant_w_kernel<<<WN / 1024, 256, 0, stream>>>(W_hh, Whq, wmax, WN);

  // xp = x @ W_xh^T + (b_xh + b_hh)   (written into d_out)
  gemm_f16_kernel<true><<<dim3(H / BN, M / BM), 256, 0, stream>>>(
      x, Wxh_h, biasc, xpb, M, H, H);

  // sequential scan; writes hs (f16, ws) and h_n (f32, d_out tail)
  rnn_scan_kernel<<<B, RT, 0, stream>>>(Whq, wmax, h0, xpb, hsb, hn, T);

  // y = hs @ W_hy^T + b_hy   (overwrites xp region of d_out)
  gemm_f16_kernel<false><<<dim3(H / BN, M / BM), 256, 0, stream>>>(
      hsb, Why_h, b_hy, out, M, H, H);
}